// Round 3
// baseline (1484.683 us; speedup 1.0000x reference)
//
#include <hip/hip_runtime.h>
#include <stdint.h>

#define T_LEN 8196
#define LOG2E 1.4426950408889634f
#define LN2   0.6931471805599453f
#define INF2  1.4426950e10f   /* 1e10 * log2(e): INF in base-2-scaled units */
#define PD_LD 2128            /* padded D row stride: 64 left + 2048 + 16 right */
#define PD_OFF 64

// ---------------------------------------------------------------- helpers
__device__ __forceinline__ float fexp2(float x) {
#if __has_builtin(__builtin_amdgcn_exp2f)
    return __builtin_amdgcn_exp2f(x);
#else
    return __expf(x * LN2);
#endif
}
__device__ __forceinline__ float flog2(float x) {
#if __has_builtin(__builtin_amdgcn_logf)
    return __builtin_amdgcn_logf(x);   // v_log_f32 is base-2
#else
    return __logf(x) * LOG2E;
#endif
}
// softmin in base-2-scaled units: out = m - log2(2^(m-a)+2^(m-b)+2^(m-c))
__device__ __forceinline__ float softmin2(float a, float b, float c) {
    float m = fminf(fminf(a, b), c);
    float s = fexp2(m - a) + fexp2(m - b) + fexp2(m - c);
    return m - flog2(s);
}
__device__ __forceinline__ float sigm(float x) { return 1.0f / (1.0f + __expf(-x)); }
__device__ __forceinline__ float tanh_f(float x) {
    x = fminf(fmaxf(x, -15.0f), 15.0f);
    float e = __expf(2.0f * x);
    return (e - 1.0f) / (e + 1.0f);
}

// ------------------------------------------- prep: transpose weights
// wt layout (floats): Wih1^T [72][384] @0, Whh1^T [128][384] @27648,
//                     Wih2^T [128][384] @76800, Whh2^T [128][384] @125952
__global__ void k_prep(const float* __restrict__ Wih1, const float* __restrict__ Whh1,
                       const float* __restrict__ Wih2, const float* __restrict__ Whh2,
                       float* __restrict__ wt) {
    int gid = blockIdx.x * 256 + threadIdx.x;
    if (gid >= 175104) return;
    if (gid < 27648) {
        int k = gid / 384, g = gid % 384;
        wt[gid] = Wih1[g * 72 + k];
    } else if (gid < 76800) {
        int r = gid - 27648; int k = r / 384, g = r % 384;
        wt[gid] = Whh1[g * 128 + k];
    } else if (gid < 125952) {
        int r = gid - 76800; int k = r / 384, g = r % 384;
        wt[gid] = Wih2[g * 128 + k];
    } else {
        int r = gid - 125952; int k = r / 384, g = r % 384;
        wt[gid] = Whh2[g * 128 + k];
    }
}

// ------------------------------------------- GRU features (unchanged from R2)
__global__ __launch_bounds__(256)
void k_gru(const float* __restrict__ X, const float* __restrict__ Y,
           const float* __restrict__ wt,
           const float* __restrict__ bih1, const float* __restrict__ bhh1,
           const float* __restrict__ bih2, const float* __restrict__ bhh2,
           const float* __restrict__ W1, const float* __restrict__ b1,
           float* __restrict__ fbuf) {
    __shared__ __align__(16) float xb[72 * 20];
    __shared__ __align__(16) float h1l[128 * 20];
    __shared__ __align__(16) float h2l[128 * 20];

    const int tid = threadIdx.x;
    const int u = tid & 127;
    const int w0 = (tid >> 7) * 8;
    const int bx = blockIdx.x;
    const int seq = bx >> 7;
    const int wbase = (bx & 127) << 4;
    const float* xp = seq ? Y : X;

    const float* wih1 = wt;
    const float* whh1 = wt + 27648;
    const float* wih2 = wt + 76800;
    const float* whh2 = wt + 125952;

    const float br1  = bih1[u] + bhh1[u];
    const float bz1  = bih1[128 + u] + bhh1[128 + u];
    const float bni1 = bih1[256 + u];
    const float bnh1 = bhh1[256 + u];
    const float br2  = bih2[u] + bhh2[u];
    const float bz2  = bih2[128 + u] + bhh2[128 + u];
    const float bni2 = bih2[256 + u];
    const float bnh2 = bhh2[256 + u];

    float h1r[8], h2r[8];
#pragma unroll
    for (int j = 0; j < 8; ++j) { h1r[j] = 0.f; h2r[j] = 0.f; }
    for (int e = tid; e < 128 * 20; e += 256) { h1l[e] = 0.f; h2l[e] = 0.f; }
    __syncthreads();

    for (int t = 0; t < 8; ++t) {
        for (int e = tid; e < 72 * 16; e += 256) {
            int k = e >> 4, w = e & 15;
            int jj = k / 3, c = k - jj * 3;
            xb[k * 20 + w] = xp[jj * (3 * T_LEN) + c * T_LEN + ((wbase + w) << 2) + t];
        }
        __syncthreads();

        float ar[8], az[8], ai[8], ah[8];
#pragma unroll
        for (int j = 0; j < 8; ++j) { ar[j] = br1; az[j] = bz1; ai[j] = bni1; ah[j] = bnh1; }
        for (int k = 0; k < 72; ++k) {
            float wr = wih1[k * 384 + u];
            float wz = wih1[k * 384 + 128 + u];
            float wn = wih1[k * 384 + 256 + u];
            const float4 x0 = *(const float4*)&xb[k * 20 + w0];
            const float4 x1 = *(const float4*)&xb[k * 20 + w0 + 4];
            float xv[8] = {x0.x, x0.y, x0.z, x0.w, x1.x, x1.y, x1.z, x1.w};
#pragma unroll
            for (int j = 0; j < 8; ++j) {
                ar[j] = fmaf(wr, xv[j], ar[j]);
                az[j] = fmaf(wz, xv[j], az[j]);
                ai[j] = fmaf(wn, xv[j], ai[j]);
            }
        }
        for (int k = 0; k < 128; ++k) {
            float wr = whh1[k * 384 + u];
            float wz = whh1[k * 384 + 128 + u];
            float wn = whh1[k * 384 + 256 + u];
            const float4 x0 = *(const float4*)&h1l[k * 20 + w0];
            const float4 x1 = *(const float4*)&h1l[k * 20 + w0 + 4];
            float xv[8] = {x0.x, x0.y, x0.z, x0.w, x1.x, x1.y, x1.z, x1.w};
#pragma unroll
            for (int j = 0; j < 8; ++j) {
                ar[j] = fmaf(wr, xv[j], ar[j]);
                az[j] = fmaf(wz, xv[j], az[j]);
                ah[j] = fmaf(wn, xv[j], ah[j]);
            }
        }
        __syncthreads();
#pragma unroll
        for (int j = 0; j < 8; ++j) {
            float r = sigm(ar[j]);
            float z = sigm(az[j]);
            float n = tanh_f(ai[j] + r * ah[j]);
            h1r[j] = (1.f - z) * n + z * h1r[j];
        }
#pragma unroll
        for (int j = 0; j < 8; ++j) h1l[u * 20 + w0 + j] = h1r[j];
        __syncthreads();

#pragma unroll
        for (int j = 0; j < 8; ++j) { ar[j] = br2; az[j] = bz2; ai[j] = bni2; ah[j] = bnh2; }
        for (int k = 0; k < 128; ++k) {
            float wr = wih2[k * 384 + u];
            float wz = wih2[k * 384 + 128 + u];
            float wn = wih2[k * 384 + 256 + u];
            const float4 x0 = *(const float4*)&h1l[k * 20 + w0];
            const float4 x1 = *(const float4*)&h1l[k * 20 + w0 + 4];
            float xv[8] = {x0.x, x0.y, x0.z, x0.w, x1.x, x1.y, x1.z, x1.w};
#pragma unroll
            for (int j = 0; j < 8; ++j) {
                ar[j] = fmaf(wr, xv[j], ar[j]);
                az[j] = fmaf(wz, xv[j], az[j]);
                ai[j] = fmaf(wn, xv[j], ai[j]);
            }
        }
        for (int k = 0; k < 128; ++k) {
            float wr = whh2[k * 384 + u];
            float wz = whh2[k * 384 + 128 + u];
            float wn = whh2[k * 384 + 256 + u];
            const float4 x0 = *(const float4*)&h2l[k * 20 + w0];
            const float4 x1 = *(const float4*)&h2l[k * 20 + w0 + 4];
            float xv[8] = {x0.x, x0.y, x0.z, x0.w, x1.x, x1.y, x1.z, x1.w};
#pragma unroll
            for (int j = 0; j < 8; ++j) {
                ar[j] = fmaf(wr, xv[j], ar[j]);
                az[j] = fmaf(wz, xv[j], az[j]);
                ah[j] = fmaf(wn, xv[j], ah[j]);
            }
        }
        __syncthreads();
#pragma unroll
        for (int j = 0; j < 8; ++j) {
            float r = sigm(ar[j]);
            float z = sigm(az[j]);
            float n = tanh_f(ai[j] + r * ah[j]);
            h2r[j] = (1.f - z) * n + z * h2r[j];
        }
#pragma unroll
        for (int j = 0; j < 8; ++j) h2l[u * 20 + w0 + j] = h2r[j];
        __syncthreads();
    }

    for (int idx = tid; idx < 16 * 30; idx += 256) {
        int w = idx / 30, ff = idx - w * 30;
        float acc = b1[ff];
        for (int k = 0; k < 128; ++k) acc = fmaf(h2l[k * 20 + w], W1[ff * 128 + k], acc);
        fbuf[(seq * 2048 + wbase + w) * 32 + ff] = acc;
    }
}

// ------------------------------------------- pairwise sqdist -> padded, base-2 scaled
__global__ __launch_bounds__(256)
void k_pair(const float* __restrict__ fbuf, float* __restrict__ Dp) {
    __shared__ float f1t[64 * 33];
    __shared__ float f2t[64 * 33];
    const int tid = threadIdx.x;
    const int i0 = blockIdx.y * 64, j0 = blockIdx.x * 64;
    for (int e = tid; e < 64 * 32; e += 256) {
        int r = e >> 5, c = e & 31;
        f1t[r * 33 + c] = fbuf[(i0 + r) * 32 + c];
        f2t[r * 33 + c] = fbuf[(2048 + j0 + r) * 32 + c];
    }
    __syncthreads();
    const int tx = tid & 15, ty = tid >> 4;
    float acc[4][4];
#pragma unroll
    for (int r = 0; r < 4; ++r)
#pragma unroll
        for (int c = 0; c < 4; ++c) acc[r][c] = 0.f;
    for (int k = 0; k < 30; ++k) {
        float a[4], b[4];
#pragma unroll
        for (int r = 0; r < 4; ++r) a[r] = f1t[(ty * 4 + r) * 33 + k];
#pragma unroll
        for (int c = 0; c < 4; ++c) b[c] = f2t[(tx * 4 + c) * 33 + k];
#pragma unroll
        for (int r = 0; r < 4; ++r)
#pragma unroll
            for (int c = 0; c < 4; ++c) {
                float d = a[r] - b[c];
                acc[r][c] = fmaf(d, d, acc[r][c]);
            }
    }
#pragma unroll
    for (int r = 0; r < 4; ++r) {
        float4 v = make_float4(acc[r][0] * LOG2E, acc[r][1] * LOG2E,
                               acc[r][2] * LOG2E, acc[r][3] * LOG2E);
        *(float4*)&Dp[(size_t)(i0 + ty * 4 + r) * PD_LD + PD_OFF + j0 + tx * 4] = v;
    }
}

// ------------------------------------------- softDTW wavefront
// 8 blocks x 64 lanes; lane i owns 4 rows r0=256b+4i .. r0+3.
// At step t lane i computes column j = t - i for its 4 rows (chain of 4 softmin).
// Cross-lane via shfl_up (hidden: 4-softmin chain > ds_permute latency).
// Cross-block boundary values: packed (tag<<32|f32) relaxed agent atomics,
// DOUBLE-BUFFERED: loads for batch k+1 issue before batch k's compute,
// tags verified after it -> poll latency off the critical chain.
#define DTW_BATCH(CUR, NXT, T0)                                                  \
  {                                                                              \
    const int t0 = (T0);                                                         \
    _Pragma("unroll")                                                            \
    for (int u = 0; u < 8; ++u) {   /* prefetch next batch's D (padded rows) */  \
        int jj = min(t0 + 8 + u - lane, 2063);                                   \
        NXT[0][u] = rowp0[jj];                                                   \
        NXT[1][u] = rowp1[jj];                                                   \
        NXT[2][u] = rowp2[jj];                                                   \
        NXT[3][u] = rowp3[jj];                                                   \
    }                                                                            \
    uint64_t pv[8];                                                              \
    if (b > 0) {                                                                 \
        _Pragma("unroll")                                                        \
        for (int u = 0; u < 8; ++u) {   /* issue next-batch boundary loads */    \
            int jc = min(t0 + 8 + u, 2047);                                      \
            pv[u] = __hip_atomic_load(&bprevp[jc], __ATOMIC_RELAXED,             \
                                      __HIP_MEMORY_SCOPE_AGENT);                 \
        }                                                                        \
    }                                                                            \
    _Pragma("unroll")                                                            \
    for (int u = 0; u < 8; ++u) {                                                \
        const int t = t0 + u;                                                    \
        const int j = t - lane;                                                  \
        const bool valid = (j >= 0) && (j < 2048);                               \
        float up0, dg0;                                                          \
        if (b == 0) { up0 = INF2; dg0 = (j == 0) ? 0.f : INF2; }                 \
        else { up0 = bnd_cur[u]; dg0 = (u == 0) ? bnd_carry : bnd_cur[u - 1]; }  \
        if (lane > 0) { up0 = s1; dg0 = s1p; }                                   \
        float v0 = valid ? (CUR[0][u] + softmin2(dg0, up0, L0)) : INF2;          \
        float v1 = valid ? (CUR[1][u] + softmin2(L0, v0, L1)) : INF2;            \
        float v2 = valid ? (CUR[2][u] + softmin2(L1, v1, L2)) : INF2;            \
        float v3 = valid ? (CUR[3][u] + softmin2(L2, v2, L3)) : INF2;            \
        s1p = s1;                                                                \
        s1 = __shfl_up(v3, 1);                                                   \
        L0 = v0; L1 = v1; L2 = v2; L3 = v3;                                      \
        if (lane == 63 && valid) {                                               \
            if (b < 7) {                                                         \
                uint64_t pk = ((uint64_t)(uint32_t)j << 32) |                    \
                              (uint64_t)__float_as_uint(v3);                     \
                __hip_atomic_store(&bminep[j], pk, __ATOMIC_RELAXED,             \
                                   __HIP_MEMORY_SCOPE_AGENT);                    \
            } else if (j == 2047) res = v3;                                      \
        }                                                                        \
    }                                                                            \
    if (b > 0) {   /* verify next-batch boundary tags, unpack */                 \
        bnd_carry = bnd_cur[7];                                                  \
        _Pragma("unroll")                                                        \
        for (int u = 0; u < 8; ++u) {                                            \
            int jc = min(t0 + 8 + u, 2047);                                      \
            while ((uint32_t)(pv[u] >> 32) != (uint32_t)jc) {                    \
                __builtin_amdgcn_s_sleep(1);                                     \
                pv[u] = __hip_atomic_load(&bprevp[jc], __ATOMIC_RELAXED,         \
                                          __HIP_MEMORY_SCOPE_AGENT);             \
            }                                                                    \
            bnd_cur[u] = __uint_as_float((uint32_t)pv[u]);                       \
        }                                                                        \
    }                                                                            \
  }

__global__ __launch_bounds__(64)
void k_dtw(const float* __restrict__ Dp, uint64_t* bndp, float* __restrict__ out) {
    const int b = blockIdx.x;
    const int lane = threadIdx.x;
    const int r0 = b * 256 + 4 * lane;
    const uint64_t* bprevp = bndp + (b - 1) * 2048;
    uint64_t* bminep = bndp + b * 2048;

    const float* rowp0 = Dp + (size_t)r0 * PD_LD + PD_OFF;
    const float* rowp1 = rowp0 + PD_LD;
    const float* rowp2 = rowp1 + PD_LD;
    const float* rowp3 = rowp2 + PD_LD;

    float L0 = INF2, L1 = INF2, L2 = INF2, L3 = INF2;  // left values (col j-1)
    float s1 = INF2, s1p = INF2;    // shfl history of lane-1's row3 values
    float bnd_carry = INF2;
    float res = 0.f;
    float bnd_cur[8];

    float dA[4][8], dB[4][8];
#pragma unroll
    for (int u = 0; u < 8; ++u) {   // preload batch 0 (left pad covers j<0)
        int jj = u - lane;
        dA[0][u] = rowp0[jj];
        dA[1][u] = rowp1[jj];
        dA[2][u] = rowp2[jj];
        dA[3][u] = rowp3[jj];
    }
    if (b > 0) {   // verify batch-0 boundary (cols 0..7)
#pragma unroll
        for (int u = 0; u < 8; ++u) {
            uint64_t p = __hip_atomic_load(&bprevp[u], __ATOMIC_RELAXED,
                                           __HIP_MEMORY_SCOPE_AGENT);
            while ((uint32_t)(p >> 32) != (uint32_t)u) {
                __builtin_amdgcn_s_sleep(1);
                p = __hip_atomic_load(&bprevp[u], __ATOMIC_RELAXED,
                                      __HIP_MEMORY_SCOPE_AGENT);
            }
            bnd_cur[u] = __uint_as_float((uint32_t)p);
        }
    }

    // 264 batches of 8 steps cover t = 0 .. 2111 (need t up to 2110)
    for (int bt = 0; bt < 264; bt += 2) {
        DTW_BATCH(dA, dB, bt * 8);
        DTW_BATCH(dB, dA, (bt + 1) * 8);
    }

    if (b == 7 && lane == 63) out[0] = res * LN2;   // back to base-e units
}

// ------------------------------------------- launch
extern "C" void kernel_launch(void* const* d_in, const int* in_sizes, int n_in,
                              void* d_out, int out_size, void* d_ws, size_t ws_size,
                              hipStream_t stream) {
    const float* X    = (const float*)d_in[0];
    const float* Y    = (const float*)d_in[1];
    const float* Wih1 = (const float*)d_in[2];
    const float* Whh1 = (const float*)d_in[3];
    const float* bih1 = (const float*)d_in[4];
    const float* bhh1 = (const float*)d_in[5];
    const float* Wih2 = (const float*)d_in[6];
    const float* Whh2 = (const float*)d_in[7];
    const float* bih2 = (const float*)d_in[8];
    const float* bhh2 = (const float*)d_in[9];
    const float* W1   = (const float*)d_in[10];
    const float* b1   = (const float*)d_in[11];
    float* out = (float*)d_out;

    // Layout (floats). wt overlaps Dp's tail: wt is dead after k_gru, and
    // k_pair (which overwrites all of Dp) runs after k_gru. Total 17.24 MB.
    float* ws   = (float*)d_ws;
    float* fbuf = ws;                            // 131072 floats
    uint64_t* bndp = (uint64_t*)(ws + 131072);   // 7*2048 u64 = 28672 floats
    float* Dp   = ws + 131072 + 28672;           // 2048*2128 = 4358144 floats
    float* wt   = Dp + 4358144 - 175104;         // overlapped tail

    k_prep<<<684, 256, 0, stream>>>(Wih1, Whh1, Wih2, Whh2, wt);
    k_gru<<<256, 256, 0, stream>>>(X, Y, wt, bih1, bhh1, bih2, bhh2, W1, b1, fbuf);
    k_pair<<<dim3(32, 32), 256, 0, stream>>>(fbuf, Dp);
    k_dtw<<<8, 64, 0, stream>>>(Dp, bndp, out);
}

// Round 4
// 1081.304 us; speedup vs baseline: 1.3730x; 1.3730x over previous
//
#include <hip/hip_runtime.h>
#include <stdint.h>

#define T_LEN 8196
#define LOG2E 1.4426950408889634f
#define LN2   0.6931471805599453f
#define INF2  1.4426950e10f   /* 1e10 * log2(e): INF in base-2-scaled units */
#define PD_LD 2128            /* padded D row stride: 64 left + 2048 + 16 right */
#define PD_OFF 64

// ---------------------------------------------------------------- helpers
__device__ __forceinline__ float fexp2(float x) {
#if __has_builtin(__builtin_amdgcn_exp2f)
    return __builtin_amdgcn_exp2f(x);
#else
    return __expf(x * LN2);
#endif
}
__device__ __forceinline__ float flog2(float x) {
#if __has_builtin(__builtin_amdgcn_logf)
    return __builtin_amdgcn_logf(x);   // v_log_f32 is base-2
#else
    return __logf(x) * LOG2E;
#endif
}
// softmin in base-2-scaled units: out = m - log2(2^(m-a)+2^(m-b)+2^(m-c))
__device__ __forceinline__ float softmin2(float a, float b, float c) {
    float m = fminf(fminf(a, b), c);
    float s = fexp2(m - a) + fexp2(m - b) + fexp2(m - c);
    return m - flog2(s);
}
__device__ __forceinline__ float sigm(float x) { return 1.0f / (1.0f + __expf(-x)); }
__device__ __forceinline__ float tanh_f(float x) {
    x = fminf(fmaxf(x, -15.0f), 15.0f);
    float e = __expf(2.0f * x);
    return (e - 1.0f) / (e + 1.0f);
}

// ------------------------------------------- prep: transpose weights
// wt layout (floats): Wih1^T [72][384] @0, Whh1^T [128][384] @27648,
//                     Wih2^T [128][384] @76800, Whh2^T [128][384] @125952
__global__ void k_prep(const float* __restrict__ Wih1, const float* __restrict__ Whh1,
                       const float* __restrict__ Wih2, const float* __restrict__ Whh2,
                       float* __restrict__ wt) {
    int gid = blockIdx.x * 256 + threadIdx.x;
    if (gid >= 175104) return;
    if (gid < 27648) {
        int k = gid / 384, g = gid % 384;
        wt[gid] = Wih1[g * 72 + k];
    } else if (gid < 76800) {
        int r = gid - 27648; int k = r / 384, g = r % 384;
        wt[gid] = Whh1[g * 128 + k];
    } else if (gid < 125952) {
        int r = gid - 76800; int k = r / 384, g = r % 384;
        wt[gid] = Wih2[g * 128 + k];
    } else {
        int r = gid - 125952; int k = r / 384, g = r % 384;
        wt[gid] = Whh2[g * 128 + k];
    }
}

// ------------------------------------------- GRU features (unchanged)
__global__ __launch_bounds__(256)
void k_gru(const float* __restrict__ X, const float* __restrict__ Y,
           const float* __restrict__ wt,
           const float* __restrict__ bih1, const float* __restrict__ bhh1,
           const float* __restrict__ bih2, const float* __restrict__ bhh2,
           const float* __restrict__ W1, const float* __restrict__ b1,
           float* __restrict__ fbuf) {
    __shared__ __align__(16) float xb[72 * 20];
    __shared__ __align__(16) float h1l[128 * 20];
    __shared__ __align__(16) float h2l[128 * 20];

    const int tid = threadIdx.x;
    const int u = tid & 127;
    const int w0 = (tid >> 7) * 8;
    const int bx = blockIdx.x;
    const int seq = bx >> 7;
    const int wbase = (bx & 127) << 4;
    const float* xp = seq ? Y : X;

    const float* wih1 = wt;
    const float* whh1 = wt + 27648;
    const float* wih2 = wt + 76800;
    const float* whh2 = wt + 125952;

    const float br1  = bih1[u] + bhh1[u];
    const float bz1  = bih1[128 + u] + bhh1[128 + u];
    const float bni1 = bih1[256 + u];
    const float bnh1 = bhh1[256 + u];
    const float br2  = bih2[u] + bhh2[u];
    const float bz2  = bih2[128 + u] + bhh2[128 + u];
    const float bni2 = bih2[256 + u];
    const float bnh2 = bhh2[256 + u];

    float h1r[8], h2r[8];
#pragma unroll
    for (int j = 0; j < 8; ++j) { h1r[j] = 0.f; h2r[j] = 0.f; }
    for (int e = tid; e < 128 * 20; e += 256) { h1l[e] = 0.f; h2l[e] = 0.f; }
    __syncthreads();

    for (int t = 0; t < 8; ++t) {
        for (int e = tid; e < 72 * 16; e += 256) {
            int k = e >> 4, w = e & 15;
            int jj = k / 3, c = k - jj * 3;
            xb[k * 20 + w] = xp[jj * (3 * T_LEN) + c * T_LEN + ((wbase + w) << 2) + t];
        }
        __syncthreads();

        float ar[8], az[8], ai[8], ah[8];
#pragma unroll
        for (int j = 0; j < 8; ++j) { ar[j] = br1; az[j] = bz1; ai[j] = bni1; ah[j] = bnh1; }
        for (int k = 0; k < 72; ++k) {
            float wr = wih1[k * 384 + u];
            float wz = wih1[k * 384 + 128 + u];
            float wn = wih1[k * 384 + 256 + u];
            const float4 x0 = *(const float4*)&xb[k * 20 + w0];
            const float4 x1 = *(const float4*)&xb[k * 20 + w0 + 4];
            float xv[8] = {x0.x, x0.y, x0.z, x0.w, x1.x, x1.y, x1.z, x1.w};
#pragma unroll
            for (int j = 0; j < 8; ++j) {
                ar[j] = fmaf(wr, xv[j], ar[j]);
                az[j] = fmaf(wz, xv[j], az[j]);
                ai[j] = fmaf(wn, xv[j], ai[j]);
            }
        }
        for (int k = 0; k < 128; ++k) {
            float wr = whh1[k * 384 + u];
            float wz = whh1[k * 384 + 128 + u];
            float wn = whh1[k * 384 + 256 + u];
            const float4 x0 = *(const float4*)&h1l[k * 20 + w0];
            const float4 x1 = *(const float4*)&h1l[k * 20 + w0 + 4];
            float xv[8] = {x0.x, x0.y, x0.z, x0.w, x1.x, x1.y, x1.z, x1.w};
#pragma unroll
            for (int j = 0; j < 8; ++j) {
                ar[j] = fmaf(wr, xv[j], ar[j]);
                az[j] = fmaf(wz, xv[j], az[j]);
                ah[j] = fmaf(wn, xv[j], ah[j]);
            }
        }
        __syncthreads();
#pragma unroll
        for (int j = 0; j < 8; ++j) {
            float r = sigm(ar[j]);
            float z = sigm(az[j]);
            float n = tanh_f(ai[j] + r * ah[j]);
            h1r[j] = (1.f - z) * n + z * h1r[j];
        }
#pragma unroll
        for (int j = 0; j < 8; ++j) h1l[u * 20 + w0 + j] = h1r[j];
        __syncthreads();

#pragma unroll
        for (int j = 0; j < 8; ++j) { ar[j] = br2; az[j] = bz2; ai[j] = bni2; ah[j] = bnh2; }
        for (int k = 0; k < 128; ++k) {
            float wr = wih2[k * 384 + u];
            float wz = wih2[k * 384 + 128 + u];
            float wn = wih2[k * 384 + 256 + u];
            const float4 x0 = *(const float4*)&h1l[k * 20 + w0];
            const float4 x1 = *(const float4*)&h1l[k * 20 + w0 + 4];
            float xv[8] = {x0.x, x0.y, x0.z, x0.w, x1.x, x1.y, x1.z, x1.w};
#pragma unroll
            for (int j = 0; j < 8; ++j) {
                ar[j] = fmaf(wr, xv[j], ar[j]);
                az[j] = fmaf(wz, xv[j], az[j]);
                ai[j] = fmaf(wn, xv[j], ai[j]);
            }
        }
        for (int k = 0; k < 128; ++k) {
            float wr = whh2[k * 384 + u];
            float wz = whh2[k * 384 + 128 + u];
            float wn = whh2[k * 384 + 256 + u];
            const float4 x0 = *(const float4*)&h2l[k * 20 + w0];
            const float4 x1 = *(const float4*)&h2l[k * 20 + w0 + 4];
            float xv[8] = {x0.x, x0.y, x0.z, x0.w, x1.x, x1.y, x1.z, x1.w};
#pragma unroll
            for (int j = 0; j < 8; ++j) {
                ar[j] = fmaf(wr, xv[j], ar[j]);
                az[j] = fmaf(wz, xv[j], az[j]);
                ah[j] = fmaf(wn, xv[j], ah[j]);
            }
        }
        __syncthreads();
#pragma unroll
        for (int j = 0; j < 8; ++j) {
            float r = sigm(ar[j]);
            float z = sigm(az[j]);
            float n = tanh_f(ai[j] + r * ah[j]);
            h2r[j] = (1.f - z) * n + z * h2r[j];
        }
#pragma unroll
        for (int j = 0; j < 8; ++j) h2l[u * 20 + w0 + j] = h2r[j];
        __syncthreads();
    }

    for (int idx = tid; idx < 16 * 30; idx += 256) {
        int w = idx / 30, ff = idx - w * 30;
        float acc = b1[ff];
        for (int k = 0; k < 128; ++k) acc = fmaf(h2l[k * 20 + w], W1[ff * 128 + k], acc);
        fbuf[(seq * 2048 + wbase + w) * 32 + ff] = acc;
    }
}

// ------------------------------------------- pairwise sqdist -> padded, base-2 scaled
__global__ __launch_bounds__(256)
void k_pair(const float* __restrict__ fbuf, float* __restrict__ Dp) {
    __shared__ float f1t[64 * 33];
    __shared__ float f2t[64 * 33];
    const int tid = threadIdx.x;
    const int i0 = blockIdx.y * 64, j0 = blockIdx.x * 64;
    for (int e = tid; e < 64 * 32; e += 256) {
        int r = e >> 5, c = e & 31;
        f1t[r * 33 + c] = fbuf[(i0 + r) * 32 + c];
        f2t[r * 33 + c] = fbuf[(2048 + j0 + r) * 32 + c];
    }
    __syncthreads();
    const int tx = tid & 15, ty = tid >> 4;
    float acc[4][4];
#pragma unroll
    for (int r = 0; r < 4; ++r)
#pragma unroll
        for (int c = 0; c < 4; ++c) acc[r][c] = 0.f;
    for (int k = 0; k < 30; ++k) {
        float a[4], b[4];
#pragma unroll
        for (int r = 0; r < 4; ++r) a[r] = f1t[(ty * 4 + r) * 33 + k];
#pragma unroll
        for (int c = 0; c < 4; ++c) b[c] = f2t[(tx * 4 + c) * 33 + k];
#pragma unroll
        for (int r = 0; r < 4; ++r)
#pragma unroll
            for (int c = 0; c < 4; ++c) {
                float d = a[r] - b[c];
                acc[r][c] = fmaf(d, d, acc[r][c]);
            }
    }
#pragma unroll
    for (int r = 0; r < 4; ++r) {
        float4 v = make_float4(acc[r][0] * LOG2E, acc[r][1] * LOG2E,
                               acc[r][2] * LOG2E, acc[r][3] * LOG2E);
        *(float4*)&Dp[(size_t)(i0 + ty * 4 + r) * PD_LD + PD_OFF + j0 + tx * 4] = v;
    }
}

// ------------------------------------------- softDTW wavefront
// 16 blocks x 64 lanes; lane i owns rows rA=128b+2i, rB=rA+1.
// At step t lane i computes column j = t - i for both rows.
// Cross-lane via shfl_up. Cross-block boundary publish via RELAXED agent
// __hip_atomic_exchange (RMW executes at the memory-side coherence point ->
// prompt cross-XCD visibility WITHOUT a fence; R2/R3's plain relaxed stores
// sat dirty in the producer's L2 until eviction, ~100-300K cyc lag/handoff).
// Boundary polls double-buffered: issued before a batch's compute, tags
// verified after it.
#define DTW_BATCH(CUR, NXT, T0)                                                  \
  {                                                                              \
    const int t0 = (T0);                                                         \
    _Pragma("unroll")                                                            \
    for (int u = 0; u < 8; ++u) {   /* prefetch next batch's D (padded rows) */  \
        int jj = min(t0 + 8 + u - lane, 2063);                                   \
        NXT[0][u] = rowp0[jj];                                                   \
        NXT[1][u] = rowp1[jj];                                                   \
    }                                                                            \
    uint64_t pv[8];                                                              \
    if (b > 0) {                                                                 \
        _Pragma("unroll")                                                        \
        for (int u = 0; u < 8; ++u) {   /* issue next-batch boundary loads */    \
            int jc = min(t0 + 8 + u, 2047);                                      \
            pv[u] = __hip_atomic_load(&bprevp[jc], __ATOMIC_RELAXED,             \
                                      __HIP_MEMORY_SCOPE_AGENT);                 \
        }                                                                        \
    }                                                                            \
    _Pragma("unroll")                                                            \
    for (int u = 0; u < 8; ++u) {                                                \
        const int t = t0 + u;                                                    \
        const int j = t - lane;                                                  \
        const bool valid = (j >= 0) && (j < 2048);                               \
        float upA, dgA;                                                          \
        if (b == 0) { upA = INF2; dgA = (j == 0) ? 0.f : INF2; }                 \
        else { upA = bnd_cur[u]; dgA = (u == 0) ? bnd_carry : bnd_cur[u - 1]; }  \
        if (lane > 0) { upA = s1; dgA = s1p; }                                   \
        float vA = valid ? (CUR[0][u] + softmin2(dgA, upA, L0)) : INF2;          \
        float vB = valid ? (CUR[1][u] + softmin2(L0, vA, L1)) : INF2;            \
        s1p = s1;                                                                \
        s1 = __shfl_up(vB, 1);                                                   \
        L0 = vA; L1 = vB;                                                        \
        if (lane == 63 && valid) {                                               \
            if (b < 15) {                                                        \
                uint64_t pk = ((uint64_t)(uint32_t)j << 32) |                    \
                              (uint64_t)__float_as_uint(vB);                     \
                (void)__hip_atomic_exchange(&bminep[j], pk, __ATOMIC_RELAXED,    \
                                            __HIP_MEMORY_SCOPE_AGENT);           \
            } else if (j == 2047) res = vB;                                      \
        }                                                                        \
    }                                                                            \
    if (b > 0) {   /* verify next-batch boundary tags, unpack */                 \
        bnd_carry = bnd_cur[7];                                                  \
        _Pragma("unroll")                                                        \
        for (int u = 0; u < 8; ++u) {                                            \
            int jc = min(t0 + 8 + u, 2047);                                      \
            while ((uint32_t)(pv[u] >> 32) != (uint32_t)jc) {                    \
                __builtin_amdgcn_s_sleep(1);                                     \
                pv[u] = __hip_atomic_load(&bprevp[jc], __ATOMIC_RELAXED,         \
                                          __HIP_MEMORY_SCOPE_AGENT);             \
            }                                                                    \
            bnd_cur[u] = __uint_as_float((uint32_t)pv[u]);                       \
        }                                                                        \
    }                                                                            \
  }

__global__ __launch_bounds__(64)
void k_dtw(const float* __restrict__ Dp, uint64_t* bndp, float* __restrict__ out) {
    const int b = blockIdx.x;
    const int lane = threadIdx.x;
    const int r0 = b * 128 + 2 * lane;
    const uint64_t* bprevp = bndp + (b - 1) * 2048;
    uint64_t* bminep = bndp + b * 2048;

    const float* rowp0 = Dp + (size_t)r0 * PD_LD + PD_OFF;
    const float* rowp1 = rowp0 + PD_LD;

    float L0 = INF2, L1 = INF2;       // left values (col j-1) for rows rA,rB
    float s1 = INF2, s1p = INF2;      // shfl history of lane-1's rB values
    float bnd_carry = INF2;
    float res = 0.f;
    float bnd_cur[8];

    float dA[2][8], dB[2][8];
#pragma unroll
    for (int u = 0; u < 8; ++u) {     // preload batch 0 (left pad covers j<0)
        int jj = u - lane;
        dA[0][u] = rowp0[jj];
        dA[1][u] = rowp1[jj];
    }
    if (b > 0) {   // verify batch-0 boundary (cols 0..7)
#pragma unroll
        for (int u = 0; u < 8; ++u) {
            uint64_t p = __hip_atomic_load(&bprevp[u], __ATOMIC_RELAXED,
                                           __HIP_MEMORY_SCOPE_AGENT);
            while ((uint32_t)(p >> 32) != (uint32_t)u) {
                __builtin_amdgcn_s_sleep(1);
                p = __hip_atomic_load(&bprevp[u], __ATOMIC_RELAXED,
                                      __HIP_MEMORY_SCOPE_AGENT);
            }
            bnd_cur[u] = __uint_as_float((uint32_t)p);
        }
    }

    // 264 batches of 8 steps cover t = 0 .. 2111 (need t up to 2110)
    for (int bt = 0; bt < 264; bt += 2) {
        DTW_BATCH(dA, dB, bt * 8);
        DTW_BATCH(dB, dA, (bt + 1) * 8);
    }

    if (b == 15 && lane == 63) out[0] = res * LN2;   // back to base-e units
}

// ------------------------------------------- launch
extern "C" void kernel_launch(void* const* d_in, const int* in_sizes, int n_in,
                              void* d_out, int out_size, void* d_ws, size_t ws_size,
                              hipStream_t stream) {
    const float* X    = (const float*)d_in[0];
    const float* Y    = (const float*)d_in[1];
    const float* Wih1 = (const float*)d_in[2];
    const float* Whh1 = (const float*)d_in[3];
    const float* bih1 = (const float*)d_in[4];
    const float* bhh1 = (const float*)d_in[5];
    const float* Wih2 = (const float*)d_in[6];
    const float* Whh2 = (const float*)d_in[7];
    const float* bih2 = (const float*)d_in[8];
    const float* bhh2 = (const float*)d_in[9];
    const float* W1   = (const float*)d_in[10];
    const float* b1   = (const float*)d_in[11];
    float* out = (float*)d_out;

    // Layout (floats). wt overlaps Dp's tail: wt is dead after k_gru, and
    // k_pair (which overwrites all of Dp) runs after k_gru. ~18.2 MB total.
    float* ws   = (float*)d_ws;
    float* fbuf = ws;                            // 131072 floats
    uint64_t* bndp = (uint64_t*)(ws + 131072);   // 15*2048 u64 = 61440 floats
    float* Dp   = ws + 131072 + 61440;           // 2048*2128 = 4358144 floats
    float* wt   = Dp + 4358144 - 175104;         // overlapped tail

    k_prep<<<684, 256, 0, stream>>>(Wih1, Whh1, Wih2, Whh2, wt);
    k_gru<<<256, 256, 0, stream>>>(X, Y, wt, bih1, bhh1, bih2, bhh2, W1, b1, fbuf);
    k_pair<<<dim3(32, 32), 256, 0, stream>>>(fbuf, Dp);
    k_dtw<<<16, 64, 0, stream>>>(Dp, bndp, out);
}